// Round 8
// baseline (32.185 us; speedup 1.0000x reference)
//
#include <hip/hip_runtime.h>

// XTermFrequency: per-row vocab frequency = histogram / rowsum.
// R7 lesson: three different structures all pin at 111MB/24us = 4.6 TB/s ->
// store-path ceiling, not phase structure. R8 attacks the store path:
//  - NON-TEMPORAL dwordx4 stores (nt): output is write-once; nt skips L3/L2
//    allocation and streams at the HBM write rate (fill kernel: 6.7 TB/s),
//    and stops 103MB from thrashing L2 (protects row-read residency).
//  - wave-per-chunk, ZERO barriers: block = 1 wave (64T) owns one 6284-bin
//    chunk (25.1KB LDS -> 6 waves/CU). Only per-wave lgkmcnt(0) syncs
//    zero->scatter->drain; co-resident waves free-run (no lockstep bubbles).
// Chunk-major grid: bid%8 == r%8 -> all 8 chunk-jobs of a row on one XCD,
// row re-reads stay L2/L3-resident.
#define VOCAB 50257
#define NCH   8
#define CHUNK 6284               // 8*6284 = 50272 >= VOCAB, /4
#define NV4   (CHUNK / 4)        // 1571 f32x4 -> 25136 B LDS

typedef float f32x4 __attribute__((ext_vector_type(4)));

__global__ __launch_bounds__(64) void XTermFrequency_5471788335935_kernel(
    const int* __restrict__ asg, const float* __restrict__ w,
    float* __restrict__ out, int S, int B)
{
    __shared__ f32x4 hist4[NV4];
    float* hist = reinterpret_cast<float*>(hist4);

    const int bid  = blockIdx.x;
    const int c    = bid / B;                // chunk index (chunk-major)
    const int r    = bid - c * B;            // row index
    const int lo   = c * CHUNK;
    const int hi   = min(CHUNK, VOCAB - lo);
    const int lane = threadIdx.x;

    const int*   __restrict__ row  = asg + (long long)r * S;
    const float* __restrict__ wrow = w   + (long long)r * S;
    float*       __restrict__ po   = out + (long long)r * VOCAB + lo;

    // ---- zero the chunk histogram (b128) ----
    const f32x4 z4 = {0.f, 0.f, 0.f, 0.f};
    for (int j = lane; j < NV4; j += 64) hist4[j] = z4;
    asm volatile("s_waitcnt lgkmcnt(0)" ::: "memory");  // zeros before atomics

    // ---- scan row: vectorized loads, LDS fadd scatter, per-lane sum ----
    float ws = 0.f;
    if ((S & 3) == 0) {
        const int4*   __restrict__ rv = reinterpret_cast<const int4*>(row);
        const float4* __restrict__ wv = reinterpret_cast<const float4*>(wrow);
        const int nq = S >> 2;
        for (int q = lane; q < nq; q += 64) {
            const int4   a4 = rv[q];
            const float4 w4 = wv[q];
            ws += (w4.x + w4.y) + (w4.z + w4.w);
            const int v0 = a4.x - lo, v1 = a4.y - lo,
                      v2 = a4.z - lo, v3 = a4.w - lo;
            if ((unsigned)v0 < (unsigned)CHUNK) atomicAdd(&hist[v0], w4.x);
            if ((unsigned)v1 < (unsigned)CHUNK) atomicAdd(&hist[v1], w4.y);
            if ((unsigned)v2 < (unsigned)CHUNK) atomicAdd(&hist[v2], w4.z);
            if ((unsigned)v3 < (unsigned)CHUNK) atomicAdd(&hist[v3], w4.w);
        }
    } else {
        for (int s = lane; s < S; s += 64) {
            const float ww = wrow[s];
            ws += ww;
            const int v = row[s] - lo;
            if ((unsigned)v < (unsigned)CHUNK) atomicAdd(&hist[v], ww);
        }
    }

    // ---- wave allreduce of row sum (butterfly; every lane gets total) ----
    #pragma unroll
    for (int off = 1; off < 64; off <<= 1) ws += __shfl_xor(ws, off, 64);
    const float inv = 1.0f / ws;             // 2^-11 exact for the bench

    // all scatters (and swizzles) complete before drain reads
    asm volatile("s_waitcnt lgkmcnt(0)" ::: "memory");

    // ---- drain: aligned b128 LDS reads, non-temporal dwordx4 stores ----
    // global dwordx4 needs only 4B alignment; nt = no-allocate streaming.
    const int nv = hi >> 2;
    for (int j = lane; j < nv; j += 64) {
        f32x4 h = hist4[j] * inv;
        float* p = po + (j << 2);
        asm volatile("global_store_dwordx4 %0, %1, off nt"
                     :: "v"(p), "v"(h));
    }
    for (int i = (nv << 2) + lane; i < hi; i += 64) {  // 0-3 element tail
        float h = hist[i] * inv;
        float* p = po + i;
        asm volatile("global_store_dword %0, %1, off nt"
                     :: "v"(p), "v"(h));
    }
}

extern "C" void kernel_launch(void* const* d_in, const int* in_sizes, int n_in,
                              void* d_out, int out_size, void* d_ws, size_t ws_size,
                              hipStream_t stream) {
    const int*   asg = (const int*)d_in[0];
    const float* w   = (const float*)d_in[1];
    float*       out = (float*)d_out;

    const int B = out_size / VOCAB;          // 512
    const int S = in_sizes[0] / B;           // 2048

    XTermFrequency_5471788335935_kernel<<<B * NCH, 64, 0, stream>>>(
        asg, w, out, S, B);
}

// Round 9
// 31.023 us; speedup vs baseline: 1.0375x; 1.0375x over previous
//
#include <hip/hip_runtime.h>

// XTermFrequency: per-row vocab frequency = histogram / rowsum.
// EXACTLY the R6 kernel (23.98us) with ONE change: `nt` on the drain stores.
// A/B test: R2/R6/R7 all pin at ~4.6 TB/s effective while the harness's
// 402MB fill streams at 6.7 TB/s -> hypothesis: writes to the L3-RESIDENT
// output are capped by the L2->L3 dirty-writeback path; `nt` (no-allocate)
// should route the write-once stream to the HBM path at fill-rate.
// R8 conflated nt with a 1-wave-block redesign; this isolates nt.
#define VOCAB  50257
#define NCHUNK 4
#define CHUNK  12565                 // 4*12565 = 50260 >= VOCAB
#define NVEC4  3142                  // padded f32x4 words (12568 floats)

typedef float f32x4 __attribute__((ext_vector_type(4)));

// Barrier ordering LDS only; global stores remain in flight.
#define LDS_BARRIER()                                            \
    do {                                                         \
        asm volatile("s_waitcnt lgkmcnt(0)" ::: "memory");       \
        __builtin_amdgcn_s_barrier();                            \
        __builtin_amdgcn_sched_barrier(0);                       \
    } while (0)

__global__ __launch_bounds__(1024) void XTermFrequency_5471788335935_kernel(
    const int* __restrict__ asg, const float* __restrict__ w,
    float* __restrict__ out, int S)
{
    __shared__ f32x4 hist4[NVEC4];           // 50272 B
    __shared__ float s_sum;
    float* hist = reinterpret_cast<float*>(hist4);

    const int b   = blockIdx.x;
    const int tid = threadIdx.x;
    const long long rowoff = (long long)b * S;
    const int*   __restrict__ row  = asg + rowoff;
    const float* __restrict__ wrow = w   + rowoff;
    float*       __restrict__ orow = out + (long long)b * VOCAB;

    // Register-cache this thread's samples when S == 2*blockDim (bench shape:
    // S=2048, block=1024). Generic fallback re-reads global in scatter phase.
    const bool cached = ((S & 1) == 0) && ((S >> 1) == (int)blockDim.x);
    int2   ra = make_int2(0, 0);
    float2 rw = make_float2(0.f, 0.f);
    float  ws = 0.f;
    if (cached) {
        ra = reinterpret_cast<const int2*>(row)[tid];
        rw = reinterpret_cast<const float2*>(wrow)[tid];
        ws = rw.x + rw.y;
    } else {
        for (int s = tid; s < S; s += blockDim.x) ws += wrow[s];
    }

    if (tid == 0) s_sum = 0.f;
    __syncthreads();
    // wave(64) shuffle reduce, one native ds-atomic per wave
    #pragma unroll
    for (int off = 32; off > 0; off >>= 1) ws += __shfl_down(ws, off, 64);
    if ((tid & 63) == 0) atomicAdd(&s_sum, ws);

    // Zero the (padded) histogram once; store loop re-zeros as it drains.
    const f32x4 z4 = {0.f, 0.f, 0.f, 0.f};
    for (int j = tid; j < NVEC4; j += 1024) hist4[j] = z4;
    LDS_BARRIER();   // zeros + s_sum visible

    const float inv = 1.0f / s_sum;   // 2^-11 exact for the bench shape

    // Stagger chunk order across blocks to spread HBM store bursts.
    const int phase = b & (NCHUNK - 1);

    for (int cc = 0; cc < NCHUNK; ++cc) {
        const int c  = (cc + phase) & (NCHUNK - 1);
        const int lo = c * CHUNK;

        // ---- scatter into LDS histogram (native ds fadd) ----
        if (cached) {
            const int v0 = ra.x - lo;
            const int v1 = ra.y - lo;
            if ((unsigned)v0 < (unsigned)CHUNK) atomicAdd(&hist[v0], rw.x);
            if ((unsigned)v1 < (unsigned)CHUNK) atomicAdd(&hist[v1], rw.y);
        } else {
            for (int s = tid; s < S; s += blockDim.x) {
                const int v = row[s] - lo;
                if ((unsigned)v < (unsigned)CHUNK) atomicAdd(&hist[v], wrow[s]);
            }
        }
        LDS_BARRIER();

        // ---- drain chunk: b128 read, b128 re-zero, nt dwordx4 store ----
        const int hi = min(CHUNK, VOCAB - lo);   // 12565 / 12562
        const int nv = hi >> 2;                  // exact f32x4 count
        for (int j = tid; j < nv; j += 1024) {
            f32x4 h = hist4[j];                  // ds_read_b128 (16B-aligned LDS)
            hist4[j] = z4;                       // ds_write_b128 re-zero
            f32x4 r = h * inv;
            float* p = orow + lo + (j << 2);     // 4B-aligned is enough for x4
            asm volatile("global_store_dwordx4 %0, %1, off nt"
                         :: "v"(p), "v"(r));
        }
        for (int i = (nv << 2) + tid; i < hi; i += 1024) {  // 1-2 element tail
            const float h = hist[i];
            hist[i] = 0.f;
            orow[lo + i] = h * inv;
        }
        LDS_BARRIER();   // zeros visible before next chunk's scatter
    }
}

extern "C" void kernel_launch(void* const* d_in, const int* in_sizes, int n_in,
                              void* d_out, int out_size, void* d_ws, size_t ws_size,
                              hipStream_t stream) {
    const int*   asg = (const int*)d_in[0];
    const float* w   = (const float*)d_in[1];
    float*       out = (float*)d_out;

    const int B = out_size / VOCAB;          // 512
    const int S = in_sizes[0] / B;           // 2048

    XTermFrequency_5471788335935_kernel<<<B, 1024, 0, stream>>>(asg, w, out, S);
}

// Round 10
// 29.732 us; speedup vs baseline: 1.0825x; 1.0434x over previous
//
#include <hip/hip_runtime.h>

// XTermFrequency: per-row vocab frequency = histogram / rowsum.
// R9 A/B: `nt` is per-se harmful (+7us). Standing fact: LDS-drain stores pin
// at ~4.6 TB/s while rocclr's pure fill does 6.7 TB/s on the same path.
// R10: split the 103MB output into the two regimes --
//   (1) pure register ZERO-FILL of the whole row (the rocclr fill pattern,
//       dependency-free dwordx4 bursts) issued fire-and-forget up front;
//   (2) R6's LDS histogram, but the drain SKIPS all-zero f32x4 words (~85%:
//       only ~1965/50257 bins are nonzero) and stores just the nonzero words.
// Sparse stores hit lines still dirty in this CU's L2 (402KB/CU << 4MB) and
// merge -> total TCC write stays ~103MB, now streamed at fill-kernel duty.
// __syncthreads() (vmcnt(0)-draining) orders fill before sparse stores.
#define VOCAB  50257
#define NCHUNK 4
#define CHUNK  12565                 // 4*12565 = 50260 >= VOCAB
#define NVEC4  3142                  // padded f32x4 words (12568 floats)

typedef float f32x4 __attribute__((ext_vector_type(4)));

// Barrier ordering LDS only; global stores remain in flight.
#define LDS_BARRIER()                                            \
    do {                                                         \
        asm volatile("s_waitcnt lgkmcnt(0)" ::: "memory");       \
        __builtin_amdgcn_s_barrier();                            \
        __builtin_amdgcn_sched_barrier(0);                       \
    } while (0)

__global__ __launch_bounds__(1024) void XTermFrequency_5471788335935_kernel(
    const int* __restrict__ asg, const float* __restrict__ w,
    float* __restrict__ out, int S)
{
    __shared__ f32x4 hist4[NVEC4];           // 50272 B -> 2 blocks/CU
    __shared__ float s_sum;
    float* hist = reinterpret_cast<float*>(hist4);

    const int b   = blockIdx.x;
    const int tid = threadIdx.x;
    const long long rowoff = (long long)b * S;
    const int*   __restrict__ row  = asg + rowoff;
    const float* __restrict__ wrow = w   + rowoff;
    float*       __restrict__ orow = out + (long long)b * VOCAB;

    // Register-cache this thread's samples when S == 2*blockDim (bench shape:
    // S=2048, block=1024). Generic fallback re-reads global in scatter phase.
    const bool cached = ((S & 1) == 0) && ((S >> 1) == (int)blockDim.x);
    int2   ra = make_int2(0, 0);
    float2 rw = make_float2(0.f, 0.f);
    float  ws = 0.f;
    if (cached) {
        ra = reinterpret_cast<const int2*>(row)[tid];
        rw = reinterpret_cast<const float2*>(wrow)[tid];
        ws = rw.x + rw.y;
    } else {
        for (int s = tid; s < S; s += blockDim.x) ws += wrow[s];
    }

    if (tid == 0) s_sum = 0.f;
    __syncthreads();
    // wave(64) shuffle reduce, one native ds-atomic per wave
    #pragma unroll
    for (int off = 32; off > 0; off >>= 1) ws += __shfl_down(ws, off, 64);
    if ((tid & 63) == 0) atomicAdd(&s_sum, ws);

    // ---- phase 1: pure zero-fill of the row (fill-kernel regime) ----
    // Head-align to 16B, dependency-free float4 body, scalar tail.
    {
        const int head0 = (int)(((16u - ((unsigned)(uintptr_t)orow & 15u)) & 15u) >> 2);
        if (tid < head0) orow[tid] = 0.f;
        const int nvec = (VOCAB - head0) >> 2;
        float4* __restrict__ vb = reinterpret_cast<float4*>(orow + head0);
        const float4 zf = make_float4(0.f, 0.f, 0.f, 0.f);
        for (int j = tid; j < nvec; j += 1024) vb[j] = zf;
        const int tpos = head0 + (nvec << 2) + tid;
        if (tid < 4 && tpos < VOCAB) orow[tpos] = 0.f;
    }

    // Zero the (padded) LDS histogram while the fill stores stream.
    const f32x4 z4 = {0.f, 0.f, 0.f, 0.f};
    for (int j = tid; j < NVEC4; j += 1024) hist4[j] = z4;

    // Drain: vmcnt(0) inside __syncthreads -> zero-fill committed at L2
    // before any sparse store below; also publishes hist zeros + s_sum.
    __syncthreads();

    const float inv = 1.0f / s_sum;   // 2^-11 exact for the bench shape

    // Stagger chunk order across blocks to spread residual store bursts.
    const int phase = b & (NCHUNK - 1);

    for (int cc = 0; cc < NCHUNK; ++cc) {
        const int c  = (cc + phase) & (NCHUNK - 1);
        const int lo = c * CHUNK;

        // ---- scatter into LDS histogram (native ds fadd) ----
        if (cached) {
            const int v0 = ra.x - lo;
            const int v1 = ra.y - lo;
            if ((unsigned)v0 < (unsigned)CHUNK) atomicAdd(&hist[v0], rw.x);
            if ((unsigned)v1 < (unsigned)CHUNK) atomicAdd(&hist[v1], rw.y);
        } else {
            for (int s = tid; s < S; s += blockDim.x) {
                const int v = row[s] - lo;
                if ((unsigned)v < (unsigned)CHUNK) atomicAdd(&hist[v], wrow[s]);
            }
        }
        LDS_BARRIER();

        // ---- sparse drain: store ONLY words containing a nonzero bin.
        // Zero positions already hold exactly 0.0f from phase 1.
        const int hi = min(CHUNK, VOCAB - lo);   // 12565 / 12562
        const int nv = hi >> 2;
        for (int j = tid; j < nv; j += 1024) {
            f32x4 h = hist4[j];                  // ds_read_b128
            if (h.x != 0.f || h.y != 0.f || h.z != 0.f || h.w != 0.f) {
                hist4[j] = z4;                   // re-zero only dirty words
                f32x4 r = h * inv;
                float* p = orow + lo + (j << 2); // 4B-aligned ok for x4
                asm volatile("global_store_dwordx4 %0, %1, off"
                             :: "v"(p), "v"(r));
            }
        }
        for (int i = (nv << 2) + tid; i < hi; i += 1024) {  // 1-2 elem tail
            const float h = hist[i];
            if (h != 0.f) {
                hist[i] = 0.f;
                orow[lo + i] = h * inv;
            }
        }
        LDS_BARRIER();   // re-zeros visible before next chunk's scatter
    }
}

extern "C" void kernel_launch(void* const* d_in, const int* in_sizes, int n_in,
                              void* d_out, int out_size, void* d_ws, size_t ws_size,
                              hipStream_t stream) {
    const int*   asg = (const int*)d_in[0];
    const float* w   = (const float*)d_in[1];
    float*       out = (float*)d_out;

    const int B = out_size / VOCAB;          // 512
    const int S = in_sizes[0] / B;           // 2048

    XTermFrequency_5471788335935_kernel<<<B, 1024, 0, stream>>>(asg, w, out, S);
}